// Round 6
// baseline (570.116 us; speedup 1.0000x reference)
//
#include <hip/hip_runtime.h>
#include <math.h>

constexpr int B = 4, C = 256, CC = 32, H = 64, W = 64, HW = H * W;
constexpr int G = 8, K = 9, GN = 32, CPG = C / GN;   // CPG = 8
constexpr int OFFC = 3 * G * K;                       // 216

typedef __attribute__((ext_vector_type(8))) short short8;
typedef __attribute__((ext_vector_type(4))) float f32x4;

__device__ inline short f2bf(float f) {
  unsigned u = __builtin_bit_cast(unsigned, f);
  return (short)((u + 0x7FFFu + ((u >> 16) & 1u)) >> 16);
}
__device__ inline float bf2f(short s) {
  unsigned u = ((unsigned)(unsigned short)s) << 16;
  return __builtin_bit_cast(float, u);
}

// ---------------- resize (2x2 avg pool: rate=2, align_corners=False) ---------
__global__ void k_resize(const float* __restrict__ in, float* __restrict__ out) {
  int idx = blockIdx.x * 256 + threadIdx.x;
  if (idx >= B * CC * HW) return;
  int p = idx & (HW - 1);
  int c = (idx / HW) % CC;
  int b = idx / (HW * CC);
  int y = p >> 6, x = p & 63;
  const float* src = in + ((size_t)b * CC + c) * (2 * H) * (2 * W);
  const float* r0 = src + (2 * y) * (2 * W) + 2 * x;
  const float* r1 = r0 + 2 * W;
  out[idx] = 0.25f * (r0[0] + r0[1] + r1[0] + r1[1]);
}

// ---------------- transpose+convert: fp32 [Csrc][HW] -> bf16 [HW][Cdst] ------
__global__ void k_transpose(const float* __restrict__ src, short* __restrict__ dst,
                            int Csrc, int Cdst, int coff) {
  int t = threadIdx.x;
  int p0 = blockIdx.x * 64;
  int cc0 = blockIdx.y * 32;
  int b = blockIdx.z;
  int px = t >> 2, cq = t & 3;
  const float* s = src + ((size_t)b * Csrc + cc0 + cq * 8) * HW + p0 + px;
  short8 v;
  #pragma unroll
  for (int j = 0; j < 8; ++j) v[j] = f2bf(s[(size_t)j * HW]);
  *(short8*)(dst + ((size_t)b * HW + p0 + px) * Cdst + coff + cc0 + cq * 8) = v;
}

// ---------------- weight transform: [Cout][Cin][T] fp32 -> [T][Cout][Cin] bf16
template<int TAPS>
__global__ void k_wt(const float* __restrict__ w, short* __restrict__ wT,
                     int Cout, int Cin) {
  int id = blockIdx.x * 256 + threadIdx.x;
  if (id >= Cout * Cin) return;
  if (TAPS == 1) {
    wT[id] = f2bf(w[id]);
  } else {
    int o = id / Cin, ci = id % Cin;
    #pragma unroll
    for (int k = 0; k < 9; ++k)
      wT[((size_t)k * Cout + o) * Cin + ci] = f2bf(w[(size_t)id * 9 + k]);
  }
}

// ---------------- MFMA implicit-GEMM conv (taps=1 or 9, pad=(taps==9)) -------
template<int CIN, int COUT, int TAPS>
__global__ __launch_bounds__(256) void k_mfma_conv(
    const short* __restrict__ gT, const short* __restrict__ wT,
    const float* __restrict__ bias, float* __restrict__ out) {
  constexpr int POS = (TAPS == 9) ? 4 * 66 : 128;   // staged positions
  constexpr int PSTR = 40;                          // u16 per position (80 B)
  __shared__ short lds[POS * PSTR];
  const int tid = threadIdx.x;
  const int lane = tid & 63, wv = tid >> 6;
  const int l15 = lane & 15, l4 = lane >> 4;
  const int b = blockIdx.z;
  const int o0 = blockIdx.y * 64;
  const int p0 = blockIdx.x * 128;
  const int y0 = p0 >> 6;                           // 2 image rows per block

  f32x4 acc[4][2];
  #pragma unroll
  for (int mt = 0; mt < 4; ++mt)
    #pragma unroll
    for (int nt = 0; nt < 2; ++nt) acc[mt][nt] = (f32x4)0.f;

  const short* gTb = gT + (size_t)b * HW * CIN;

  for (int ck = 0; ck < CIN / 32; ++ck) {
    const int ci0 = ck * 32;
    __syncthreads();
    for (int i = tid; i < POS * 4; i += 256) {
      int pos = i >> 2, cq = i & 3;
      short8 v = {0, 0, 0, 0, 0, 0, 0, 0};
      if (TAPS == 9) {
        int r = pos / 66;
        int cx = pos - r * 66 - 1;
        int y = y0 - 1 + r;
        if ((unsigned)y < (unsigned)H && (unsigned)cx < (unsigned)W)
          v = *(const short8*)(gTb + (size_t)(y * W + cx) * CIN + ci0 + cq * 8);
      } else {
        v = *(const short8*)(gTb + (size_t)(p0 + pos) * CIN + ci0 + cq * 8);
      }
      *(short8*)(lds + pos * PSTR + cq * 8) = v;
    }
    __syncthreads();

    for (int tap = 0; tap < TAPS; ++tap) {
      short8 a[4];
      #pragma unroll
      for (int mt = 0; mt < 4; ++mt) {
        int o_r = o0 + mt * 16 + l15;
        if (COUT % 64 == 0 || o_r < COUT)
          a[mt] = *(const short8*)(wT + ((size_t)tap * COUT + o_r) * CIN + ci0 + l4 * 8);
        else
          a[mt] = (short8){0, 0, 0, 0, 0, 0, 0, 0};
      }
      short8 bb[2];
      #pragma unroll
      for (int nt = 0; nt < 2; ++nt) {
        int pos;
        if (TAPS == 9) {
          int dy = tap / 3 - 1, dx = tap % 3 - 1;
          int row = (wv >> 1) + dy + 1;
          int col = (wv & 1) * 32 + nt * 16 + l15 + dx + 1;
          pos = row * 66 + col;
        } else {
          pos = wv * 32 + nt * 16 + l15;
        }
        bb[nt] = *(const short8*)(lds + pos * PSTR + l4 * 8);
      }
      #pragma unroll
      for (int mt = 0; mt < 4; ++mt)
        #pragma unroll
        for (int nt = 0; nt < 2; ++nt)
          acc[mt][nt] = __builtin_amdgcn_mfma_f32_16x16x32_bf16(
              a[mt], bb[nt], acc[mt][nt], 0, 0, 0);
    }
  }

  #pragma unroll
  for (int mt = 0; mt < 4; ++mt) {
    #pragma unroll
    for (int nt = 0; nt < 2; ++nt) {
      int p = p0 + wv * 32 + nt * 16 + l15;
      #pragma unroll
      for (int r = 0; r < 4; ++r) {
        int oo = o0 + mt * 16 + l4 * 4 + r;
        if (COUT % 64 == 0 || oo < COUT)
          out[((size_t)b * COUT + oo) * HW + p] = acc[mt][nt][r] + bias[oo];
      }
    }
  }
}

// ---------------- GroupNorm + SiLU (fp32 in-place variant, for gn1) ----------
__global__ void k_gn_silu(const float* __restrict__ in, float* __restrict__ out,
                          const float* __restrict__ gamma, const float* __restrict__ beta) {
  int g = blockIdx.x, b = blockIdx.y;
  const float* base = in + ((size_t)b * C + g * CPG) * HW;
  float s = 0.f, s2 = 0.f;
  for (int i = threadIdx.x; i < CPG * HW; i += 256) {
    float v = base[i]; s += v; s2 += v * v;
  }
  #pragma unroll
  for (int off = 32; off > 0; off >>= 1) {
    s  += __shfl_down(s, off);
    s2 += __shfl_down(s2, off);
  }
  __shared__ float sh[8];
  __shared__ float mi[2];
  int wid = threadIdx.x >> 6, lane = threadIdx.x & 63;
  if (lane == 0) { sh[wid] = s; sh[4 + wid] = s2; }
  __syncthreads();
  if (threadIdx.x == 0) {
    float ts = sh[0] + sh[1] + sh[2] + sh[3];
    float t2 = sh[4] + sh[5] + sh[6] + sh[7];
    float mean = ts * (1.f / (CPG * HW));
    float var  = t2 * (1.f / (CPG * HW)) - mean * mean;
    mi[0] = mean; mi[1] = rsqrtf(var + 1e-6f);
  }
  __syncthreads();
  float mean = mi[0], inv = mi[1];
  float* ob = out + ((size_t)b * C + g * CPG) * HW;
  for (int i = threadIdx.x; i < CPG * HW; i += 256) {
    int c = g * CPG + (i >> 12);
    float v = (base[i] - mean) * inv * gamma[c] + beta[c];
    ob[i] = v / (1.f + expf(-v));
  }
}

// ---------------- GN stats pass: mean + rsqrt(var) per (group, b) ------------
__global__ void k_gn_stats(const float* __restrict__ in, float2* __restrict__ stats) {
  int g = blockIdx.x, b = blockIdx.y;
  const float* base = in + ((size_t)b * C + g * CPG) * HW;
  float s = 0.f, s2 = 0.f;
  for (int i = threadIdx.x; i < CPG * HW; i += 256) {
    float v = base[i]; s += v; s2 += v * v;
  }
  #pragma unroll
  for (int off = 32; off > 0; off >>= 1) {
    s  += __shfl_down(s, off);
    s2 += __shfl_down(s2, off);
  }
  __shared__ float sh[8];
  int wid = threadIdx.x >> 6, lane = threadIdx.x & 63;
  if (lane == 0) { sh[wid] = s; sh[4 + wid] = s2; }
  __syncthreads();
  if (threadIdx.x == 0) {
    float ts = sh[0] + sh[1] + sh[2] + sh[3];
    float t2 = sh[4] + sh[5] + sh[6] + sh[7];
    float mean = ts * (1.f / (CPG * HW));
    float var  = t2 * (1.f / (CPG * HW)) - mean * mean;
    stats[b * GN + g] = make_float2(mean, rsqrtf(var + 1e-6f));
  }
}

// ------- GN apply + SiLU + transpose to bf16 [HW][C] (opt. fp32 out too) -----
template<int WRITE_F32>
__global__ void k_gnt(const float* __restrict__ in, const float2* __restrict__ stats,
                      const float* __restrict__ gamma, const float* __restrict__ beta,
                      short* __restrict__ T, float* __restrict__ outf) {
  int t = threadIdx.x;
  int p0 = blockIdx.x * 64;
  int b = blockIdx.y;
  int px = t >> 2, cq = t & 3;
  int p = p0 + px;
  #pragma unroll
  for (int cc0 = 0; cc0 < C; cc0 += 32) {
    int cbase = cc0 + cq * 8;
    float2 mi = stats[b * GN + (cbase >> 3)];
    short8 v;
    #pragma unroll
    for (int j = 0; j < 8; ++j) {
      int c = cbase + j;
      float x = in[((size_t)b * C + c) * HW + p];
      float y = (x - mi.x) * mi.y * gamma[c] + beta[c];
      y = y / (1.f + expf(-y));
      if (WRITE_F32) outf[((size_t)b * C + c) * HW + p] = y;
      v[j] = f2bf(y);
    }
    *(short8*)(T + ((size_t)b * HW + p) * C + cbase) = v;
  }
}

// ---------------- depthwise 7x7, pad 3 — 4 px per thread, float4 row loads ---
__global__ void k_dw7(const float* __restrict__ in, const float* __restrict__ w,
                      const float* __restrict__ bias, float* __restrict__ out) {
  int t = blockIdx.x * 256 + threadIdx.x;   // 0..1023 per (c,b)
  int c = blockIdx.y, b = blockIdx.z;
  int x4 = (t & 15) * 4;
  int y = t >> 4;
  const float* src = in + ((size_t)b * C + c) * HW;
  const float* wk = w + c * 49;
  float bz = bias[c];
  float a0 = bz, a1 = bz, a2 = bz, a3 = bz;
  const float4 z4 = make_float4(0.f, 0.f, 0.f, 0.f);
  #pragma unroll
  for (int ky = 0; ky < 7; ++ky) {
    int yy = y + ky - 3;
    if ((unsigned)yy >= (unsigned)H) continue;
    const float* row = src + yy * W;
    float4 A = (x4 >= 4)  ? *(const float4*)(row + x4 - 4) : z4;
    float4 Bm = *(const float4*)(row + x4);
    float4 Cx = (x4 <= 56) ? *(const float4*)(row + x4 + 4) : z4;
    float rb[12] = {A.x, A.y, A.z, A.w, Bm.x, Bm.y, Bm.z, Bm.w, Cx.x, Cx.y, Cx.z, Cx.w};
    #pragma unroll
    for (int kx = 0; kx < 7; ++kx) {
      float wv = wk[ky * 7 + kx];
      a0 += wv * rb[kx + 1];
      a1 += wv * rb[kx + 2];
      a2 += wv * rb[kx + 3];
      a3 += wv * rb[kx + 4];
    }
  }
  *(float4*)(out + ((size_t)b * C + c) * HW + y * W + x4) = make_float4(a0, a1, a2, a3);
}

// ---------------- modulated deformable conv 3x3 via MFMA (v6) ----------------
// 1024 threads = 16 waves = 4 px-quarters x 4 o-tiles; 64-px tile (one row).
// Weights for (g, 3-tap chunk) staged in LDS (shared by all waves) -> per-CU
// weight L2 traffic halved vs v3. Samples go straight into per-lane B-frag
// registers (lane l15 = pixel, l4 = channel-quad): no sample LDS, no barriers
// except around weight staging (2 per chunk).
__global__ __launch_bounds__(1024) void k_deform_mfma(
    const short* __restrict__ xmT, const float* __restrict__ co,
    const short* __restrict__ wT, const float* __restrict__ bias,
    float* __restrict__ out) {
  constexpr int WSTR = 40;                       // u16 per (tap,o) row (80 B)
  __shared__ short wlds[3 * 256 * WSTR];         // 60 KB
  const int tid = threadIdx.x;
  const int lane = tid & 63, wv = tid >> 6;
  const int l15 = lane & 15, l4 = lane >> 4;
  const int b = blockIdx.y;
  const int p0 = blockIdx.x * 64;                // one image row
  const int pq = wv & 3;                         // px quarter (16 px)
  const int ot = wv >> 2;                        // o-tile (64 outs)
  const int o0 = ot * 64;

  f32x4 acc[4];
  #pragma unroll
  for (int mt = 0; mt < 4; ++mt) acc[mt] = (f32x4)0.f;

  const short* xb = xmT + (size_t)b * HW * C;
  const float* cob = co + (size_t)b * OFFC * HW;
  const int p = p0 + pq * 16 + l15;
  const int py = p >> 6, px = p & 63;

  for (int g = 0; g < G; ++g) {
    const short* xg = xb + g * 32 + l4 * 8;
    for (int c3 = 0; c3 < 3; ++c3) {
      __syncthreads();
      // stage weights for taps {3*c3..3*c3+2}, all 256 outs, 32 ch of group g
      #pragma unroll
      for (int it = 0; it < 3; ++it) {
        int i = tid + it * 1024;
        int tap3 = i >> 10, o = (i >> 2) & 255, cq = i & 3;
        short8 v = *(const short8*)(wT + ((size_t)(3 * c3 + tap3) * 256 + o) * 256 + g * 32 + cq * 8);
        *(short8*)(wlds + (tap3 * 256 + o) * WSTR + cq * 8) = v;
      }
      __syncthreads();
      #pragma unroll
      for (int t3 = 0; t3 < 3; ++t3) {
        const int k = 3 * c3 + t3;
        // --- sample B-fragment in registers (lane: pixel l15, chans l4*8..) --
        float dy = cob[(size_t)((g * K + k) * 2) * HW + p];
        float dx = cob[(size_t)((g * K + k) * 2 + 1) * HW + p];
        float ml = cob[(size_t)(144 + g * K + k) * HW + p];
        float m = 1.f / (1.f + expf(-ml));
        int kh = k / 3 - 1, kw = k % 3 - 1;
        float yy = (float)(py + kh) + dy;
        float xx = (float)(px + kw) + dx;
        float yf = floorf(yy), xf = floorf(xx);
        float wy = yy - yf, wx = xx - xf;
        int y0 = (int)yf, x0 = (int)xf;
        bool yv0 = (unsigned)y0 < (unsigned)H, yv1 = (unsigned)(y0 + 1) < (unsigned)H;
        bool xv0 = (unsigned)x0 < (unsigned)W, xv1 = (unsigned)(x0 + 1) < (unsigned)W;
        int yc0 = min(max(y0, 0), H - 1), yc1 = min(max(y0 + 1, 0), H - 1);
        int xc0 = min(max(x0, 0), W - 1), xc1 = min(max(x0 + 1, 0), W - 1);
        float w00 = (yv0 && xv0) ? (1.f - wy) * (1.f - wx) * m : 0.f;
        float w01 = (yv0 && xv1) ? (1.f - wy) * wx * m : 0.f;
        float w10 = (yv1 && xv0) ? wy * (1.f - wx) * m : 0.f;
        float w11 = (yv1 && xv1) ? wy * wx * m : 0.f;
        short8 v00 = *(const short8*)(xg + (size_t)(yc0 * W + xc0) * C);
        short8 v01 = *(const short8*)(xg + (size_t)(yc0 * W + xc1) * C);
        short8 v10 = *(const short8*)(xg + (size_t)(yc1 * W + xc0) * C);
        short8 v11 = *(const short8*)(xg + (size_t)(yc1 * W + xc1) * C);
        short8 bb;
        #pragma unroll
        for (int j = 0; j < 8; ++j)
          bb[j] = f2bf(w00 * bf2f(v00[j]) + w01 * bf2f(v01[j]) +
                       w10 * bf2f(v10[j]) + w11 * bf2f(v11[j]));
        // --- 4 MFMAs with A from LDS ---------------------------------------
        #pragma unroll
        for (int mt = 0; mt < 4; ++mt) {
          short8 a = *(const short8*)(wlds + (t3 * 256 + o0 + mt * 16 + l15) * WSTR + l4 * 8);
          acc[mt] = __builtin_amdgcn_mfma_f32_16x16x32_bf16(a, bb, acc[mt], 0, 0, 0);
        }
      }
    }
  }

  #pragma unroll
  for (int mt = 0; mt < 4; ++mt) {
    #pragma unroll
    for (int r = 0; r < 4; ++r) {
      int oo = o0 + mt * 16 + l4 * 4 + r;
      out[((size_t)b * C + oo) * HW + p0 + pq * 16 + l15] = acc[mt][r] + bias[oo];
    }
  }
}

extern "C" void kernel_launch(void* const* d_in, const int* in_sizes, int n_in,
                              void* d_out, int out_size, void* d_ws, size_t ws_size,
                              hipStream_t stream) {
  const float* x_main  = (const float*)d_in[0];
  const float* inpfeat = (const float*)d_in[1];
  const float* w1a = (const float*)d_in[2];
  const float* b1a = (const float*)d_in[3];
  const float* g1  = (const float*)d_in[4];
  const float* be1 = (const float*)d_in[5];
  const float* w1b = (const float*)d_in[6];
  const float* b1b = (const float*)d_in[7];
  const float* g2  = (const float*)d_in[8];
  const float* be2 = (const float*)d_in[9];
  const float* w1c = (const float*)d_in[10];
  const float* b1c = (const float*)d_in[11];
  const float* w2  = (const float*)d_in[12];
  const float* b2  = (const float*)d_in[13];
  const float* g3  = (const float*)d_in[14];
  const float* be3 = (const float*)d_in[15];
  const float* w_off = (const float*)d_in[16];
  const float* b_off = (const float*)d_in[17];
  const float* w_dcn = (const float*)d_in[18];
  const float* b_dcn = (const float*)d_in[19];

  float* warp_out = (float*)d_out;                      // output 0 [B,C,H,W]
  float* off_out  = warp_out + (size_t)B * C * HW;      // output 1 [B,C,H,W]

  // ---- workspace carve (bytes) ----
  char* ws = (char*)d_ws;
  float* r_inp = (float*)ws;                            //  2 MB [B][CC][HW]; later wTd
  float* fA    = (float*)(ws + (2u << 20));             // 16 MB [B][C][HW] (also co)
  short* T     = (short*)(ws + (2u << 20) + (16u << 20));   // 9.44 MB bf16 (also xmT)
  char*  wbase = ws + (2u << 20) + (16u << 20) + 9437184;
  short* wT1a  = (short*)(wbase);                       // 256*288
  short* wT1c  = (short*)(wbase + 294912);              // 256*256
  short* wT2   = (short*)(wbase + 294912 + 131072);     // 9*256*256
  short* wToff = (short*)(wbase + 294912 + 131072 + 1179648);  // 9*216*256
  float2* stats = (float2*)(wbase + 294912 + 131072 + 1179648 + 995328);  // 128 float2
  short* wTd   = (short*)r_inp;                         // 9*256*256 (after r_inp dead)
  float* fB = warp_out;   // scratch until final deform write
  float* co = fA;

  k_wt<1><<<dim3((256 * 288 + 255) / 256), 256, 0, stream>>>(w1a, wT1a, 256, 288);
  k_wt<1><<<dim3(256), 256, 0, stream>>>(w1c, wT1c, 256, 256);
  k_wt<9><<<dim3(256), 256, 0, stream>>>(w2, wT2, 256, 256);
  k_wt<9><<<dim3(216), 256, 0, stream>>>(w_off, wToff, 216, 256);

  k_resize<<<dim3((B * CC * HW) / 256), 256, 0, stream>>>(inpfeat, r_inp);
  k_transpose<<<dim3(HW / 64, 1, B), 256, 0, stream>>>(r_inp, T, CC, 288, 0);
  k_transpose<<<dim3(HW / 64, 8, B), 256, 0, stream>>>(x_main, T, C, 288, 32);
  k_mfma_conv<288, 256, 1><<<dim3(HW / 128, 4, B), 256, 0, stream>>>(T, wT1a, b1a, fA);
  k_wt<9><<<dim3(256), 256, 0, stream>>>(w_dcn, wTd, 256, 256);   // r_inp now dead
  k_gn_silu<<<dim3(GN, B), 256, 0, stream>>>(fA, fA, g1, be1);
  k_dw7<<<dim3(HW / 1024, C, B), 256, 0, stream>>>(fA, w1b, b1b, fB);
  // gn2 fused: stats + (apply + SiLU + bf16 transpose)
  k_gn_stats<<<dim3(GN, B), 256, 0, stream>>>(fB, stats);
  k_gnt<0><<<dim3(HW / 64, B), 256, 0, stream>>>(fB, stats, g2, be2, T, nullptr);
  k_mfma_conv<256, 256, 1><<<dim3(HW / 128, 4, B), 256, 0, stream>>>(T, wT1c, b1c, fA);
  k_transpose<<<dim3(HW / 64, 8, B), 256, 0, stream>>>(fA, T, C, 256, 0);
  k_mfma_conv<256, 256, 9><<<dim3(HW / 128, 4, B), 256, 0, stream>>>(T, wT2, b2, fB);
  // gn3 fused: stats + (apply + SiLU + fp32 off_out + bf16 transpose)
  k_gn_stats<<<dim3(GN, B), 256, 0, stream>>>(fB, stats);
  k_gnt<1><<<dim3(HW / 64, B), 256, 0, stream>>>(fB, stats, g3, be3, T, off_out);
  k_mfma_conv<256, 216, 9><<<dim3(HW / 128, 4, B), 256, 0, stream>>>(T, wToff, b_off, co);
  // T dead -> reuse as xmT [B][HW][256] bf16
  k_transpose<<<dim3(HW / 64, 8, B), 256, 0, stream>>>(x_main, T, C, 256, 0);
  k_deform_mfma<<<dim3(HW / 64, B), 1024, 0, stream>>>(T, co, wTd, b_dcn, warp_out);
}

// Round 7
// 552.322 us; speedup vs baseline: 1.0322x; 1.0322x over previous
//
#include <hip/hip_runtime.h>
#include <math.h>

constexpr int B = 4, C = 256, CC = 32, H = 64, W = 64, HW = H * W;
constexpr int G = 8, K = 9, GN = 32, CPG = C / GN;   // CPG = 8
constexpr int OFFC = 3 * G * K;                       // 216

typedef __attribute__((ext_vector_type(8))) short short8;
typedef __attribute__((ext_vector_type(4))) float f32x4;

__device__ inline short f2bf(float f) {
  unsigned u = __builtin_bit_cast(unsigned, f);
  return (short)((u + 0x7FFFu + ((u >> 16) & 1u)) >> 16);
}
__device__ inline float bf2f(short s) {
  unsigned u = ((unsigned)(unsigned short)s) << 16;
  return __builtin_bit_cast(float, u);
}

// ---------------- resize (2x2 avg pool: rate=2, align_corners=False) ---------
__global__ void k_resize(const float* __restrict__ in, float* __restrict__ out) {
  int idx = blockIdx.x * 256 + threadIdx.x;
  if (idx >= B * CC * HW) return;
  int p = idx & (HW - 1);
  int c = (idx / HW) % CC;
  int b = idx / (HW * CC);
  int y = p >> 6, x = p & 63;
  const float* src = in + ((size_t)b * CC + c) * (2 * H) * (2 * W);
  const float* r0 = src + (2 * y) * (2 * W) + 2 * x;
  const float* r1 = r0 + 2 * W;
  out[idx] = 0.25f * (r0[0] + r0[1] + r1[0] + r1[1]);
}

// ---------------- transpose+convert: fp32 [Csrc][HW] -> bf16 [HW][Cdst] ------
__global__ void k_transpose(const float* __restrict__ src, short* __restrict__ dst,
                            int Csrc, int Cdst, int coff) {
  int t = threadIdx.x;
  int p0 = blockIdx.x * 64;
  int cc0 = blockIdx.y * 32;
  int b = blockIdx.z;
  int px = t >> 2, cq = t & 3;
  const float* s = src + ((size_t)b * Csrc + cc0 + cq * 8) * HW + p0 + px;
  short8 v;
  #pragma unroll
  for (int j = 0; j < 8; ++j) v[j] = f2bf(s[(size_t)j * HW]);
  *(short8*)(dst + ((size_t)b * HW + p0 + px) * Cdst + coff + cc0 + cq * 8) = v;
}

// ---------------- weight transform: [Cout][Cin][T] fp32 -> [T][Cout][Cin] bf16
template<int TAPS>
__global__ void k_wt(const float* __restrict__ w, short* __restrict__ wT,
                     int Cout, int Cin) {
  int id = blockIdx.x * 256 + threadIdx.x;
  if (id >= Cout * Cin) return;
  if (TAPS == 1) {
    wT[id] = f2bf(w[id]);
  } else {
    int o = id / Cin, ci = id % Cin;
    #pragma unroll
    for (int k = 0; k < 9; ++k)
      wT[((size_t)k * Cout + o) * Cin + ci] = f2bf(w[(size_t)id * 9 + k]);
  }
}

// ------- dcn weight transform: [256 o][256 ci][9] -> [g][tap][o][32] bf16 ----
__global__ void k_wt_dcn(const float* __restrict__ w, short* __restrict__ wT) {
  int id = blockIdx.x * 256 + threadIdx.x;   // o*256 + ci
  int o = id >> 8, ci = id & 255;
  int g = ci >> 5, cg = ci & 31;
  #pragma unroll
  for (int k = 0; k < 9; ++k)
    wT[(((size_t)g * 9 + k) * 256 + o) * 32 + cg] = f2bf(w[(size_t)id * 9 + k]);
}

// ---------------- MFMA implicit-GEMM conv (taps=1 or 9, pad=(taps==9)) -------
template<int CIN, int COUT, int TAPS>
__global__ __launch_bounds__(256) void k_mfma_conv(
    const short* __restrict__ gT, const short* __restrict__ wT,
    const float* __restrict__ bias, float* __restrict__ out) {
  constexpr int POS = (TAPS == 9) ? 4 * 66 : 128;   // staged positions
  constexpr int PSTR = 40;                          // u16 per position (80 B)
  __shared__ short lds[POS * PSTR];
  const int tid = threadIdx.x;
  const int lane = tid & 63, wv = tid >> 6;
  const int l15 = lane & 15, l4 = lane >> 4;
  const int b = blockIdx.z;
  const int o0 = blockIdx.y * 64;
  const int p0 = blockIdx.x * 128;
  const int y0 = p0 >> 6;                           // 2 image rows per block

  f32x4 acc[4][2];
  #pragma unroll
  for (int mt = 0; mt < 4; ++mt)
    #pragma unroll
    for (int nt = 0; nt < 2; ++nt) acc[mt][nt] = (f32x4)0.f;

  const short* gTb = gT + (size_t)b * HW * CIN;

  for (int ck = 0; ck < CIN / 32; ++ck) {
    const int ci0 = ck * 32;
    __syncthreads();
    for (int i = tid; i < POS * 4; i += 256) {
      int pos = i >> 2, cq = i & 3;
      short8 v = {0, 0, 0, 0, 0, 0, 0, 0};
      if (TAPS == 9) {
        int r = pos / 66;
        int cx = pos - r * 66 - 1;
        int y = y0 - 1 + r;
        if ((unsigned)y < (unsigned)H && (unsigned)cx < (unsigned)W)
          v = *(const short8*)(gTb + (size_t)(y * W + cx) * CIN + ci0 + cq * 8);
      } else {
        v = *(const short8*)(gTb + (size_t)(p0 + pos) * CIN + ci0 + cq * 8);
      }
      *(short8*)(lds + pos * PSTR + cq * 8) = v;
    }
    __syncthreads();

    for (int tap = 0; tap < TAPS; ++tap) {
      short8 a[4];
      #pragma unroll
      for (int mt = 0; mt < 4; ++mt) {
        int o_r = o0 + mt * 16 + l15;
        if (COUT % 64 == 0 || o_r < COUT)
          a[mt] = *(const short8*)(wT + ((size_t)tap * COUT + o_r) * CIN + ci0 + l4 * 8);
        else
          a[mt] = (short8){0, 0, 0, 0, 0, 0, 0, 0};
      }
      short8 bb[2];
      #pragma unroll
      for (int nt = 0; nt < 2; ++nt) {
        int pos;
        if (TAPS == 9) {
          int dy = tap / 3 - 1, dx = tap % 3 - 1;
          int row = (wv >> 1) + dy + 1;
          int col = (wv & 1) * 32 + nt * 16 + l15 + dx + 1;
          pos = row * 66 + col;
        } else {
          pos = wv * 32 + nt * 16 + l15;
        }
        bb[nt] = *(const short8*)(lds + pos * PSTR + l4 * 8);
      }
      #pragma unroll
      for (int mt = 0; mt < 4; ++mt)
        #pragma unroll
        for (int nt = 0; nt < 2; ++nt)
          acc[mt][nt] = __builtin_amdgcn_mfma_f32_16x16x32_bf16(
              a[mt], bb[nt], acc[mt][nt], 0, 0, 0);
    }
  }

  #pragma unroll
  for (int mt = 0; mt < 4; ++mt) {
    #pragma unroll
    for (int nt = 0; nt < 2; ++nt) {
      int p = p0 + wv * 32 + nt * 16 + l15;
      #pragma unroll
      for (int r = 0; r < 4; ++r) {
        int oo = o0 + mt * 16 + l4 * 4 + r;
        if (COUT % 64 == 0 || oo < COUT)
          out[((size_t)b * COUT + oo) * HW + p] = acc[mt][nt][r] + bias[oo];
      }
    }
  }
}

// ---------------- GroupNorm + SiLU (fp32 in-place variant, for gn1) ----------
__global__ void k_gn_silu(const float* __restrict__ in, float* __restrict__ out,
                          const float* __restrict__ gamma, const float* __restrict__ beta) {
  int g = blockIdx.x, b = blockIdx.y;
  const float* base = in + ((size_t)b * C + g * CPG) * HW;
  float s = 0.f, s2 = 0.f;
  for (int i = threadIdx.x; i < CPG * HW; i += 256) {
    float v = base[i]; s += v; s2 += v * v;
  }
  #pragma unroll
  for (int off = 32; off > 0; off >>= 1) {
    s  += __shfl_down(s, off);
    s2 += __shfl_down(s2, off);
  }
  __shared__ float sh[8];
  __shared__ float mi[2];
  int wid = threadIdx.x >> 6, lane = threadIdx.x & 63;
  if (lane == 0) { sh[wid] = s; sh[4 + wid] = s2; }
  __syncthreads();
  if (threadIdx.x == 0) {
    float ts = sh[0] + sh[1] + sh[2] + sh[3];
    float t2 = sh[4] + sh[5] + sh[6] + sh[7];
    float mean = ts * (1.f / (CPG * HW));
    float var  = t2 * (1.f / (CPG * HW)) - mean * mean;
    mi[0] = mean; mi[1] = rsqrtf(var + 1e-6f);
  }
  __syncthreads();
  float mean = mi[0], inv = mi[1];
  float* ob = out + ((size_t)b * C + g * CPG) * HW;
  for (int i = threadIdx.x; i < CPG * HW; i += 256) {
    int c = g * CPG + (i >> 12);
    float v = (base[i] - mean) * inv * gamma[c] + beta[c];
    ob[i] = v / (1.f + expf(-v));
  }
}

// ---------------- GN stats pass: mean + rsqrt(var) per (group, b) ------------
__global__ void k_gn_stats(const float* __restrict__ in, float2* __restrict__ stats) {
  int g = blockIdx.x, b = blockIdx.y;
  const float* base = in + ((size_t)b * C + g * CPG) * HW;
  float s = 0.f, s2 = 0.f;
  for (int i = threadIdx.x; i < CPG * HW; i += 256) {
    float v = base[i]; s += v; s2 += v * v;
  }
  #pragma unroll
  for (int off = 32; off > 0; off >>= 1) {
    s  += __shfl_down(s, off);
    s2 += __shfl_down(s2, off);
  }
  __shared__ float sh[8];
  int wid = threadIdx.x >> 6, lane = threadIdx.x & 63;
  if (lane == 0) { sh[wid] = s; sh[4 + wid] = s2; }
  __syncthreads();
  if (threadIdx.x == 0) {
    float ts = sh[0] + sh[1] + sh[2] + sh[3];
    float t2 = sh[4] + sh[5] + sh[6] + sh[7];
    float mean = ts * (1.f / (CPG * HW));
    float var  = t2 * (1.f / (CPG * HW)) - mean * mean;
    stats[b * GN + g] = make_float2(mean, rsqrtf(var + 1e-6f));
  }
}

// ------- GN apply + SiLU + transpose to bf16 [HW][C] (opt. fp32 out too) -----
template<int WRITE_F32>
__global__ void k_gnt(const float* __restrict__ in, const float2* __restrict__ stats,
                      const float* __restrict__ gamma, const float* __restrict__ beta,
                      short* __restrict__ T, float* __restrict__ outf) {
  int t = threadIdx.x;
  int p0 = blockIdx.x * 64;
  int b = blockIdx.y;
  int px = t >> 2, cq = t & 3;
  int p = p0 + px;
  #pragma unroll
  for (int cc0 = 0; cc0 < C; cc0 += 32) {
    int cbase = cc0 + cq * 8;
    float2 mi = stats[b * GN + (cbase >> 3)];
    short8 v;
    #pragma unroll
    for (int j = 0; j < 8; ++j) {
      int c = cbase + j;
      float x = in[((size_t)b * C + c) * HW + p];
      float y = (x - mi.x) * mi.y * gamma[c] + beta[c];
      y = y / (1.f + expf(-y));
      if (WRITE_F32) outf[((size_t)b * C + c) * HW + p] = y;
      v[j] = f2bf(y);
    }
    *(short8*)(T + ((size_t)b * HW + p) * C + cbase) = v;
  }
}

// ---------------- depthwise 7x7, pad 3 — 4 px per thread, float4 row loads ---
__global__ void k_dw7(const float* __restrict__ in, const float* __restrict__ w,
                      const float* __restrict__ bias, float* __restrict__ out) {
  int t = blockIdx.x * 256 + threadIdx.x;   // 0..1023 per (c,b)
  int c = blockIdx.y, b = blockIdx.z;
  int x4 = (t & 15) * 4;
  int y = t >> 4;
  const float* src = in + ((size_t)b * C + c) * HW;
  const float* wk = w + c * 49;
  float bz = bias[c];
  float a0 = bz, a1 = bz, a2 = bz, a3 = bz;
  const float4 z4 = make_float4(0.f, 0.f, 0.f, 0.f);
  #pragma unroll
  for (int ky = 0; ky < 7; ++ky) {
    int yy = y + ky - 3;
    if ((unsigned)yy >= (unsigned)H) continue;
    const float* row = src + yy * W;
    float4 A = (x4 >= 4)  ? *(const float4*)(row + x4 - 4) : z4;
    float4 Bm = *(const float4*)(row + x4);
    float4 Cx = (x4 <= 56) ? *(const float4*)(row + x4 + 4) : z4;
    float rb[12] = {A.x, A.y, A.z, A.w, Bm.x, Bm.y, Bm.z, Bm.w, Cx.x, Cx.y, Cx.z, Cx.w};
    #pragma unroll
    for (int kx = 0; kx < 7; ++kx) {
      float wv = wk[ky * 7 + kx];
      a0 += wv * rb[kx + 1];
      a1 += wv * rb[kx + 2];
      a2 += wv * rb[kx + 3];
      a3 += wv * rb[kx + 4];
    }
  }
  *(float4*)(out + ((size_t)b * C + c) * HW + y * W + x4) = make_float4(a0, a1, a2, a3);
}

// ---------------- modulated deformable conv 3x3 via MFMA (v7) ----------------
// 32-px tile, 512 threads (8 waves = 4 o-tiles x 2 px-16s), grid 512 =
// 2 blocks/CU. Cooperative 1x sampling into double-buffered LDS; stage(g+1)
// overlaps MFMA(g); one barrier per group. wTd layout [g][tap][o][32ch] ->
// A-fragment wave-loads are 1KB fully-coalesced.
__global__ __launch_bounds__(512, 4) void k_deform_mfma(
    const short* __restrict__ xmT, const float* __restrict__ co,
    const short* __restrict__ wT, const float* __restrict__ bias,
    float* __restrict__ out) {
  constexpr int PSTR = 40;                  // u16 per pixel slot (80 B)
  __shared__ short s[2][K * 32 * PSTR];     // 2 x 23040 B
  const int tid = threadIdx.x;
  const int lane = tid & 63, wv = tid >> 6;
  const int l15 = lane & 15, l4 = lane >> 4;
  const int b = blockIdx.y;
  const int p0 = blockIdx.x * 32;
  const int pt = wv & 1;                    // px 16-group
  const int o0 = (wv >> 1) * 64;            // o-tile

  f32x4 acc[4];
  #pragma unroll
  for (int mt = 0; mt < 4; ++mt) acc[mt] = (f32x4)0.f;

  const short* xb = xmT + (size_t)b * HW * C;
  const float* cob = co + (size_t)b * OFFC * HW;

  auto stage1 = [&](int g, short* sb, int i) {
    int tap = i >> 7, r = i & 127, pl = r >> 2, cq = r & 3;
    int p = p0 + pl;
    float dy = cob[(size_t)((g * K + tap) * 2) * HW + p];
    float dx = cob[(size_t)((g * K + tap) * 2 + 1) * HW + p];
    float ml = cob[(size_t)(144 + g * K + tap) * HW + p];
    float m = 1.f / (1.f + expf(-ml));
    int kh = tap / 3 - 1, kw = tap % 3 - 1;
    int py = p >> 6, px = p & 63;
    float yy = (float)(py + kh) + dy;
    float xx = (float)(px + kw) + dx;
    float yf = floorf(yy), xf = floorf(xx);
    float wy = yy - yf, wx = xx - xf;
    int y0 = (int)yf, x0 = (int)xf;
    bool yv0 = (unsigned)y0 < (unsigned)H, yv1 = (unsigned)(y0 + 1) < (unsigned)H;
    bool xv0 = (unsigned)x0 < (unsigned)W, xv1 = (unsigned)(x0 + 1) < (unsigned)W;
    int yc0 = min(max(y0, 0), H - 1), yc1 = min(max(y0 + 1, 0), H - 1);
    int xc0 = min(max(x0, 0), W - 1), xc1 = min(max(x0 + 1, 0), W - 1);
    float w00 = (yv0 && xv0) ? (1.f - wy) * (1.f - wx) * m : 0.f;
    float w01 = (yv0 && xv1) ? (1.f - wy) * wx * m : 0.f;
    float w10 = (yv1 && xv0) ? wy * (1.f - wx) * m : 0.f;
    float w11 = (yv1 && xv1) ? wy * wx * m : 0.f;
    const short* xg = xb + g * 32 + cq * 8;
    short8 v00 = *(const short8*)(xg + (size_t)(yc0 * W + xc0) * C);
    short8 v01 = *(const short8*)(xg + (size_t)(yc0 * W + xc1) * C);
    short8 v10 = *(const short8*)(xg + (size_t)(yc1 * W + xc0) * C);
    short8 v11 = *(const short8*)(xg + (size_t)(yc1 * W + xc1) * C);
    short8 rr;
    #pragma unroll
    for (int j = 0; j < 8; ++j)
      rr[j] = f2bf(w00 * bf2f(v00[j]) + w01 * bf2f(v01[j]) +
                   w10 * bf2f(v10[j]) + w11 * bf2f(v11[j]));
    *(short8*)(sb + (tap * 32 + pl) * PSTR + cq * 8) = rr;
  };
  auto stage = [&](int g, int buf) {
    short* sb = s[buf];
    stage1(g, sb, tid);
    stage1(g, sb, tid + 512);
    if (tid < K * 128 - 1024) stage1(g, sb, tid + 1024);
  };

  stage(0, 0);
  __syncthreads();
  for (int g = 0; g < G; ++g) {
    if (g < G - 1) stage(g + 1, (g + 1) & 1);
    const short* sb = s[g & 1];
    for (int k = 0; k < K; ++k) {
      short8 bb = *(const short8*)(sb + (k * 32 + pt * 16 + l15) * PSTR + l4 * 8);
      #pragma unroll
      for (int mt = 0; mt < 4; ++mt) {
        short8 a = *(const short8*)(wT + (((size_t)g * K + k) * 256 + o0 + mt * 16 + l15) * 32 + l4 * 8);
        acc[mt] = __builtin_amdgcn_mfma_f32_16x16x32_bf16(a, bb, acc[mt], 0, 0, 0);
      }
    }
    __syncthreads();
  }

  const int p = p0 + pt * 16 + l15;
  #pragma unroll
  for (int mt = 0; mt < 4; ++mt) {
    #pragma unroll
    for (int r = 0; r < 4; ++r) {
      int oo = o0 + mt * 16 + l4 * 4 + r;
      out[((size_t)b * C + oo) * HW + p] = acc[mt][r] + bias[oo];
    }
  }
}

extern "C" void kernel_launch(void* const* d_in, const int* in_sizes, int n_in,
                              void* d_out, int out_size, void* d_ws, size_t ws_size,
                              hipStream_t stream) {
  const float* x_main  = (const float*)d_in[0];
  const float* inpfeat = (const float*)d_in[1];
  const float* w1a = (const float*)d_in[2];
  const float* b1a = (const float*)d_in[3];
  const float* g1  = (const float*)d_in[4];
  const float* be1 = (const float*)d_in[5];
  const float* w1b = (const float*)d_in[6];
  const float* b1b = (const float*)d_in[7];
  const float* g2  = (const float*)d_in[8];
  const float* be2 = (const float*)d_in[9];
  const float* w1c = (const float*)d_in[10];
  const float* b1c = (const float*)d_in[11];
  const float* w2  = (const float*)d_in[12];
  const float* b2  = (const float*)d_in[13];
  const float* g3  = (const float*)d_in[14];
  const float* be3 = (const float*)d_in[15];
  const float* w_off = (const float*)d_in[16];
  const float* b_off = (const float*)d_in[17];
  const float* w_dcn = (const float*)d_in[18];
  const float* b_dcn = (const float*)d_in[19];

  float* warp_out = (float*)d_out;                      // output 0 [B,C,H,W]
  float* off_out  = warp_out + (size_t)B * C * HW;      // output 1 [B,C,H,W]

  // ---- workspace carve (bytes) ----
  char* ws = (char*)d_ws;
  float* r_inp = (float*)ws;                            //  2 MB [B][CC][HW]; later wTd
  float* fA    = (float*)(ws + (2u << 20));             // 16 MB [B][C][HW] (also co)
  short* T     = (short*)(ws + (2u << 20) + (16u << 20));   // 9.44 MB bf16 (also xmT)
  char*  wbase = ws + (2u << 20) + (16u << 20) + 9437184;
  short* wT1a  = (short*)(wbase);                       // 256*288
  short* wT1c  = (short*)(wbase + 294912);              // 256*256
  short* wT2   = (short*)(wbase + 294912 + 131072);     // 9*256*256
  short* wToff = (short*)(wbase + 294912 + 131072 + 1179648);  // 9*216*256
  float2* stats = (float2*)(wbase + 294912 + 131072 + 1179648 + 995328);  // 128 float2
  short* wTd   = (short*)r_inp;                         // [g][tap][o][32] (after r_inp dead)
  float* fB = warp_out;   // scratch until final deform write
  float* co = fA;

  k_wt<1><<<dim3((256 * 288 + 255) / 256), 256, 0, stream>>>(w1a, wT1a, 256, 288);
  k_wt<1><<<dim3(256), 256, 0, stream>>>(w1c, wT1c, 256, 256);
  k_wt<9><<<dim3(256), 256, 0, stream>>>(w2, wT2, 256, 256);
  k_wt<9><<<dim3(216), 256, 0, stream>>>(w_off, wToff, 216, 256);

  k_resize<<<dim3((B * CC * HW) / 256), 256, 0, stream>>>(inpfeat, r_inp);
  k_transpose<<<dim3(HW / 64, 1, B), 256, 0, stream>>>(r_inp, T, CC, 288, 0);
  k_transpose<<<dim3(HW / 64, 8, B), 256, 0, stream>>>(x_main, T, C, 288, 32);
  k_mfma_conv<288, 256, 1><<<dim3(HW / 128, 4, B), 256, 0, stream>>>(T, wT1a, b1a, fA);
  k_wt_dcn<<<dim3(256), 256, 0, stream>>>(w_dcn, wTd);   // r_inp now dead
  k_gn_silu<<<dim3(GN, B), 256, 0, stream>>>(fA, fA, g1, be1);
  k_dw7<<<dim3(HW / 1024, C, B), 256, 0, stream>>>(fA, w1b, b1b, fB);
  // gn2 fused: stats + (apply + SiLU + bf16 transpose)
  k_gn_stats<<<dim3(GN, B), 256, 0, stream>>>(fB, stats);
  k_gnt<0><<<dim3(HW / 64, B), 256, 0, stream>>>(fB, stats, g2, be2, T, nullptr);
  k_mfma_conv<256, 256, 1><<<dim3(HW / 128, 4, B), 256, 0, stream>>>(T, wT1c, b1c, fA);
  k_transpose<<<dim3(HW / 64, 8, B), 256, 0, stream>>>(fA, T, C, 256, 0);
  k_mfma_conv<256, 256, 9><<<dim3(HW / 128, 4, B), 256, 0, stream>>>(T, wT2, b2, fB);
  // gn3 fused: stats + (apply + SiLU + fp32 off_out + bf16 transpose)
  k_gn_stats<<<dim3(GN, B), 256, 0, stream>>>(fB, stats);
  k_gnt<1><<<dim3(HW / 64, B), 256, 0, stream>>>(fB, stats, g3, be3, T, off_out);
  k_mfma_conv<256, 216, 9><<<dim3(HW / 128, 4, B), 256, 0, stream>>>(T, wToff, b_off, co);
  // T dead -> reuse as xmT [B][HW][256] bf16
  k_transpose<<<dim3(HW / 64, 8, B), 256, 0, stream>>>(x_main, T, C, 256, 0);
  k_deform_mfma<<<dim3(HW / 32, B), 512, 0, stream>>>(T, co, wTd, b_dcn, warp_out);
}

// Round 8
// 498.558 us; speedup vs baseline: 1.1435x; 1.1078x over previous
//
#include <hip/hip_runtime.h>
#include <math.h>

constexpr int B = 4, C = 256, CC = 32, H = 64, W = 64, HW = H * W;
constexpr int G = 8, K = 9, GN = 32, CPG = C / GN;   // CPG = 8
constexpr int OFFC = 3 * G * K;                       // 216

typedef __attribute__((ext_vector_type(8))) short short8;
typedef __attribute__((ext_vector_type(4))) float f32x4;

__device__ inline short f2bf(float f) {
  unsigned u = __builtin_bit_cast(unsigned, f);
  return (short)((u + 0x7FFFu + ((u >> 16) & 1u)) >> 16);
}
__device__ inline float bf2f(short s) {
  unsigned u = ((unsigned)(unsigned short)s) << 16;
  return __builtin_bit_cast(float, u);
}

// ---------------- resize (2x2 avg pool: rate=2, align_corners=False) ---------
__global__ void k_resize(const float* __restrict__ in, float* __restrict__ out) {
  int idx = blockIdx.x * 256 + threadIdx.x;
  if (idx >= B * CC * HW) return;
  int p = idx & (HW - 1);
  int c = (idx / HW) % CC;
  int b = idx / (HW * CC);
  int y = p >> 6, x = p & 63;
  const float* src = in + ((size_t)b * CC + c) * (2 * H) * (2 * W);
  const float* r0 = src + (2 * y) * (2 * W) + 2 * x;
  const float* r1 = r0 + 2 * W;
  out[idx] = 0.25f * (r0[0] + r0[1] + r1[0] + r1[1]);
}

// ---------------- transpose+convert: fp32 [Csrc][HW] -> bf16 [HW][Cdst] ------
__global__ void k_transpose(const float* __restrict__ src, short* __restrict__ dst,
                            int Csrc, int Cdst, int coff) {
  int t = threadIdx.x;
  int p0 = blockIdx.x * 64;
  int cc0 = blockIdx.y * 32;
  int b = blockIdx.z;
  int px = t >> 2, cq = t & 3;
  const float* s = src + ((size_t)b * Csrc + cc0 + cq * 8) * HW + p0 + px;
  short8 v;
  #pragma unroll
  for (int j = 0; j < 8; ++j) v[j] = f2bf(s[(size_t)j * HW]);
  *(short8*)(dst + ((size_t)b * HW + p0 + px) * Cdst + coff + cc0 + cq * 8) = v;
}

// ---------------- weight transform: [Cout][Cin][T] fp32 -> [T][Cout][Cin] bf16
template<int TAPS>
__global__ void k_wt(const float* __restrict__ w, short* __restrict__ wT,
                     int Cout, int Cin) {
  int id = blockIdx.x * 256 + threadIdx.x;
  if (id >= Cout * Cin) return;
  if (TAPS == 1) {
    wT[id] = f2bf(w[id]);
  } else {
    int o = id / Cin, ci = id % Cin;
    #pragma unroll
    for (int k = 0; k < 9; ++k)
      wT[((size_t)k * Cout + o) * Cin + ci] = f2bf(w[(size_t)id * 9 + k]);
  }
}

// ------- dcn weight transform: [256 o][256 ci][9] -> [g][tap][o][32] bf16 ----
__global__ void k_wt_dcn(const float* __restrict__ w, short* __restrict__ wT) {
  int id = blockIdx.x * 256 + threadIdx.x;   // o*256 + ci
  int o = id >> 8, ci = id & 255;
  int g = ci >> 5, cg = ci & 31;
  #pragma unroll
  for (int k = 0; k < 9; ++k)
    wT[(((size_t)g * 9 + k) * 256 + o) * 32 + cg] = f2bf(w[(size_t)id * 9 + k]);
}

// ---------------- MFMA implicit-GEMM conv (taps=1 or 9, pad=(taps==9)) -------
// XCD-swizzled block decode: each XCD gets a contiguous chunk of the grid
// (one image + a weight half) so its L2 stays hot.
template<int CIN, int COUT, int TAPS>
__global__ __launch_bounds__(256) void k_mfma_conv(
    const short* __restrict__ gT, const short* __restrict__ wT,
    const float* __restrict__ bias, float* __restrict__ out) {
  constexpr int POS = (TAPS == 9) ? 4 * 66 : 128;   // staged positions
  constexpr int PSTR = 40;                          // u16 per position (80 B)
  __shared__ short lds[POS * PSTR];
  const int tid = threadIdx.x;
  const int lane = tid & 63, wv = tid >> 6;
  const int l15 = lane & 15, l4 = lane >> 4;
  const int lin = blockIdx.x + gridDim.x * (blockIdx.y + gridDim.y * blockIdx.z);
  const int nb = gridDim.x * gridDim.y * gridDim.z;   // 512, %8==0
  const int swz = (lin & 7) * (nb >> 3) + (lin >> 3);
  const int bx = swz % gridDim.x;
  const int rem = swz / gridDim.x;
  const int b = rem / gridDim.y;
  const int o0 = (rem % gridDim.y) * 64;
  const int p0 = bx * 128;
  const int y0 = p0 >> 6;                           // 2 image rows per block

  f32x4 acc[4][2];
  #pragma unroll
  for (int mt = 0; mt < 4; ++mt)
    #pragma unroll
    for (int nt = 0; nt < 2; ++nt) acc[mt][nt] = (f32x4)0.f;

  const short* gTb = gT + (size_t)b * HW * CIN;

  for (int ck = 0; ck < CIN / 32; ++ck) {
    const int ci0 = ck * 32;
    __syncthreads();
    for (int i = tid; i < POS * 4; i += 256) {
      int pos = i >> 2, cq = i & 3;
      short8 v = {0, 0, 0, 0, 0, 0, 0, 0};
      if (TAPS == 9) {
        int r = pos / 66;
        int cx = pos - r * 66 - 1;
        int y = y0 - 1 + r;
        if ((unsigned)y < (unsigned)H && (unsigned)cx < (unsigned)W)
          v = *(const short8*)(gTb + (size_t)(y * W + cx) * CIN + ci0 + cq * 8);
      } else {
        v = *(const short8*)(gTb + (size_t)(p0 + pos) * CIN + ci0 + cq * 8);
      }
      *(short8*)(lds + pos * PSTR + cq * 8) = v;
    }
    __syncthreads();

    for (int tap = 0; tap < TAPS; ++tap) {
      short8 a[4];
      #pragma unroll
      for (int mt = 0; mt < 4; ++mt) {
        int o_r = o0 + mt * 16 + l15;
        if (COUT % 64 == 0 || o_r < COUT)
          a[mt] = *(const short8*)(wT + ((size_t)tap * COUT + o_r) * CIN + ci0 + l4 * 8);
        else
          a[mt] = (short8){0, 0, 0, 0, 0, 0, 0, 0};
      }
      short8 bb[2];
      #pragma unroll
      for (int nt = 0; nt < 2; ++nt) {
        int pos;
        if (TAPS == 9) {
          int dy = tap / 3 - 1, dx = tap % 3 - 1;
          int row = (wv >> 1) + dy + 1;
          int col = (wv & 1) * 32 + nt * 16 + l15 + dx + 1;
          pos = row * 66 + col;
        } else {
          pos = wv * 32 + nt * 16 + l15;
        }
        bb[nt] = *(const short8*)(lds + pos * PSTR + l4 * 8);
      }
      #pragma unroll
      for (int mt = 0; mt < 4; ++mt)
        #pragma unroll
        for (int nt = 0; nt < 2; ++nt)
          acc[mt][nt] = __builtin_amdgcn_mfma_f32_16x16x32_bf16(
              a[mt], bb[nt], acc[mt][nt], 0, 0, 0);
    }
  }

  #pragma unroll
  for (int mt = 0; mt < 4; ++mt) {
    #pragma unroll
    for (int nt = 0; nt < 2; ++nt) {
      int p = p0 + wv * 32 + nt * 16 + l15;
      #pragma unroll
      for (int r = 0; r < 4; ++r) {
        int oo = o0 + mt * 16 + l4 * 4 + r;
        if (COUT % 64 == 0 || oo < COUT)
          out[((size_t)b * COUT + oo) * HW + p] = acc[mt][nt][r] + bias[oo];
      }
    }
  }
}

// ---------------- GroupNorm + SiLU (fp32 in-place variant, for gn1) ----------
__global__ void k_gn_silu(const float* __restrict__ in, float* __restrict__ out,
                          const float* __restrict__ gamma, const float* __restrict__ beta) {
  int g = blockIdx.x, b = blockIdx.y;
  const float* base = in + ((size_t)b * C + g * CPG) * HW;
  float s = 0.f, s2 = 0.f;
  for (int i = threadIdx.x; i < CPG * HW; i += 256) {
    float v = base[i]; s += v; s2 += v * v;
  }
  #pragma unroll
  for (int off = 32; off > 0; off >>= 1) {
    s  += __shfl_down(s, off);
    s2 += __shfl_down(s2, off);
  }
  __shared__ float sh[8];
  __shared__ float mi[2];
  int wid = threadIdx.x >> 6, lane = threadIdx.x & 63;
  if (lane == 0) { sh[wid] = s; sh[4 + wid] = s2; }
  __syncthreads();
  if (threadIdx.x == 0) {
    float ts = sh[0] + sh[1] + sh[2] + sh[3];
    float t2 = sh[4] + sh[5] + sh[6] + sh[7];
    float mean = ts * (1.f / (CPG * HW));
    float var  = t2 * (1.f / (CPG * HW)) - mean * mean;
    mi[0] = mean; mi[1] = rsqrtf(var + 1e-6f);
  }
  __syncthreads();
  float mean = mi[0], inv = mi[1];
  float* ob = out + ((size_t)b * C + g * CPG) * HW;
  for (int i = threadIdx.x; i < CPG * HW; i += 256) {
    int c = g * CPG + (i >> 12);
    float v = (base[i] - mean) * inv * gamma[c] + beta[c];
    ob[i] = v / (1.f + expf(-v));
  }
}

// ---------------- GN stats pass: mean + rsqrt(var) per (group, b) ------------
__global__ void k_gn_stats(const float* __restrict__ in, float2* __restrict__ stats) {
  int g = blockIdx.x, b = blockIdx.y;
  const float* base = in + ((size_t)b * C + g * CPG) * HW;
  float s = 0.f, s2 = 0.f;
  for (int i = threadIdx.x; i < CPG * HW; i += 256) {
    float v = base[i]; s += v; s2 += v * v;
  }
  #pragma unroll
  for (int off = 32; off > 0; off >>= 1) {
    s  += __shfl_down(s, off);
    s2 += __shfl_down(s2, off);
  }
  __shared__ float sh[8];
  int wid = threadIdx.x >> 6, lane = threadIdx.x & 63;
  if (lane == 0) { sh[wid] = s; sh[4 + wid] = s2; }
  __syncthreads();
  if (threadIdx.x == 0) {
    float ts = sh[0] + sh[1] + sh[2] + sh[3];
    float t2 = sh[4] + sh[5] + sh[6] + sh[7];
    float mean = ts * (1.f / (CPG * HW));
    float var  = t2 * (1.f / (CPG * HW)) - mean * mean;
    stats[b * GN + g] = make_float2(mean, rsqrtf(var + 1e-6f));
  }
}

// ------- GN apply + SiLU + transpose to bf16 [HW][C] (opt. fp32 out too) -----
template<int WRITE_F32>
__global__ void k_gnt(const float* __restrict__ in, const float2* __restrict__ stats,
                      const float* __restrict__ gamma, const float* __restrict__ beta,
                      short* __restrict__ T, float* __restrict__ outf) {
  int t = threadIdx.x;
  int p0 = blockIdx.x * 64;
  int b = blockIdx.y;
  int px = t >> 2, cq = t & 3;
  int p = p0 + px;
  #pragma unroll
  for (int cc0 = 0; cc0 < C; cc0 += 32) {
    int cbase = cc0 + cq * 8;
    float2 mi = stats[b * GN + (cbase >> 3)];
    short8 v;
    #pragma unroll
    for (int j = 0; j < 8; ++j) {
      int c = cbase + j;
      float x = in[((size_t)b * C + c) * HW + p];
      float y = (x - mi.x) * mi.y * gamma[c] + beta[c];
      y = y / (1.f + expf(-y));
      if (WRITE_F32) outf[((size_t)b * C + c) * HW + p] = y;
      v[j] = f2bf(y);
    }
    *(short8*)(T + ((size_t)b * HW + p) * C + cbase) = v;
  }
}

// ---------------- depthwise 7x7, pad 3 — 4 px per thread, float4 row loads ---
__global__ void k_dw7(const float* __restrict__ in, const float* __restrict__ w,
                      const float* __restrict__ bias, float* __restrict__ out) {
  int t = blockIdx.x * 256 + threadIdx.x;   // 0..1023 per (c,b)
  int c = blockIdx.y, b = blockIdx.z;
  int x4 = (t & 15) * 4;
  int y = t >> 4;
  const float* src = in + ((size_t)b * C + c) * HW;
  const float* wk = w + c * 49;
  float bz = bias[c];
  float a0 = bz, a1 = bz, a2 = bz, a3 = bz;
  const float4 z4 = make_float4(0.f, 0.f, 0.f, 0.f);
  #pragma unroll
  for (int ky = 0; ky < 7; ++ky) {
    int yy = y + ky - 3;
    if ((unsigned)yy >= (unsigned)H) continue;
    const float* row = src + yy * W;
    float4 A = (x4 >= 4)  ? *(const float4*)(row + x4 - 4) : z4;
    float4 Bm = *(const float4*)(row + x4);
    float4 Cx = (x4 <= 56) ? *(const float4*)(row + x4 + 4) : z4;
    float rb[12] = {A.x, A.y, A.z, A.w, Bm.x, Bm.y, Bm.z, Bm.w, Cx.x, Cx.y, Cx.z, Cx.w};
    #pragma unroll
    for (int kx = 0; kx < 7; ++kx) {
      float wv = wk[ky * 7 + kx];
      a0 += wv * rb[kx + 1];
      a1 += wv * rb[kx + 2];
      a2 += wv * rb[kx + 3];
      a3 += wv * rb[kx + 4];
    }
  }
  *(float4*)(out + ((size_t)b * C + c) * HW + y * W + x4) = make_float4(a0, a1, a2, a3);
}

// ---------------- modulated deformable conv 3x3 via MFMA (v8) ----------------
// v7 + XCD-contiguous block swizzle (per-XCD working set ~4MB -> L2-hot) +
// co prefetched one group ahead (latency under MFMA) + all 12 gather loads
// of a stage issued before first use (one L2 latency per group, not per item).
__global__ __launch_bounds__(512, 4) void k_deform_mfma(
    const short* __restrict__ xmT, const float* __restrict__ co,
    const short* __restrict__ wT, const float* __restrict__ bias,
    float* __restrict__ out) {
  constexpr int PSTR = 40;                  // u16 per pixel slot (80 B)
  __shared__ short s[2][K * 32 * PSTR];     // 2 x 23040 B
  const int tid = threadIdx.x;
  const int lane = tid & 63, wv = tid >> 6;
  const int l15 = lane & 15, l4 = lane >> 4;
  const int lin = blockIdx.x + gridDim.x * blockIdx.y;
  const int nb = gridDim.x * gridDim.y;     // 512, %8==0
  const int swz = (lin & 7) * (nb >> 3) + (lin >> 3);
  const int b = swz / (HW / 32);
  const int p0 = (swz % (HW / 32)) * 32;
  const int pt = wv & 1;                    // px 16-group
  const int o0 = (wv >> 1) * 64;            // o-tile

  f32x4 acc[4];
  #pragma unroll
  for (int mt = 0; mt < 4; ++mt) acc[mt] = (f32x4)0.f;

  const short* xb = xmT + (size_t)b * HW * C;
  const float* cob = co + (size_t)b * OFFC * HW;

  float cdy[3], cdx[3], cml[3];

  auto loadco = [&](int g) {
    #pragma unroll
    for (int j = 0; j < 3; ++j) {
      if (j == 2 && tid >= 128) continue;
      int i = tid + j * 512;
      int tap = i >> 7, pl = (i & 127) >> 2;
      int p = p0 + pl;
      cdy[j] = cob[(size_t)((g * K + tap) * 2) * HW + p];
      cdx[j] = cob[(size_t)((g * K + tap) * 2 + 1) * HW + p];
      cml[j] = cob[(size_t)(144 + g * K + tap) * HW + p];
    }
  };

  auto stage = [&](int g, short* sb) {
    float w00[3], w01[3], w10[3], w11[3];
    short8 v00[3], v01[3], v10[3], v11[3];
    int la[3];
    // issue all gathers first (independent, 12 loads in flight)
    #pragma unroll
    for (int j = 0; j < 3; ++j) {
      if (j == 2 && tid >= 128) continue;
      int i = tid + j * 512;
      int tap = i >> 7, r = i & 127, pl = r >> 2, cq = r & 3;
      int p = p0 + pl;
      float m = 1.f / (1.f + expf(-cml[j]));
      int kh = tap / 3 - 1, kw = tap % 3 - 1;
      int py = p >> 6, px = p & 63;
      float yy = (float)(py + kh) + cdy[j];
      float xx = (float)(px + kw) + cdx[j];
      float yf = floorf(yy), xf = floorf(xx);
      float wy = yy - yf, wx = xx - xf;
      int y0 = (int)yf, x0 = (int)xf;
      bool yv0 = (unsigned)y0 < (unsigned)H, yv1 = (unsigned)(y0 + 1) < (unsigned)H;
      bool xv0 = (unsigned)x0 < (unsigned)W, xv1 = (unsigned)(x0 + 1) < (unsigned)W;
      int yc0 = min(max(y0, 0), H - 1), yc1 = min(max(y0 + 1, 0), H - 1);
      int xc0 = min(max(x0, 0), W - 1), xc1 = min(max(x0 + 1, 0), W - 1);
      w00[j] = (yv0 && xv0) ? (1.f - wy) * (1.f - wx) * m : 0.f;
      w01[j] = (yv0 && xv1) ? (1.f - wy) * wx * m : 0.f;
      w10[j] = (yv1 && xv0) ? wy * (1.f - wx) * m : 0.f;
      w11[j] = (yv1 && xv1) ? wy * wx * m : 0.f;
      const short* xg = xb + g * 32 + cq * 8;
      v00[j] = *(const short8*)(xg + (size_t)(yc0 * W + xc0) * C);
      v01[j] = *(const short8*)(xg + (size_t)(yc0 * W + xc1) * C);
      v10[j] = *(const short8*)(xg + (size_t)(yc1 * W + xc0) * C);
      v11[j] = *(const short8*)(xg + (size_t)(yc1 * W + xc1) * C);
      la[j] = (tap * 32 + pl) * PSTR + cq * 8;
    }
    // then combine + write
    #pragma unroll
    for (int j = 0; j < 3; ++j) {
      if (j == 2 && tid >= 128) continue;
      short8 rr;
      #pragma unroll
      for (int jj = 0; jj < 8; ++jj)
        rr[jj] = f2bf(w00[j] * bf2f(v00[j][jj]) + w01[j] * bf2f(v01[j][jj]) +
                      w10[j] * bf2f(v10[j][jj]) + w11[j] * bf2f(v11[j][jj]));
      *(short8*)(sb + la[j]) = rr;
    }
  };

  loadco(0);
  stage(0, s[0]);
  __syncthreads();
  for (int g = 0; g < G; ++g) {
    if (g < G - 1) loadco(g + 1);           // co(g+1) flies under MFMA(g)
    const short* sb = s[g & 1];
    for (int k = 0; k < K; ++k) {
      short8 bb = *(const short8*)(sb + (k * 32 + pt * 16 + l15) * PSTR + l4 * 8);
      #pragma unroll
      for (int mt = 0; mt < 4; ++mt) {
        short8 a = *(const short8*)(wT + (((size_t)g * K + k) * 256 + o0 + mt * 16 + l15) * 32 + l4 * 8);
        acc[mt] = __builtin_amdgcn_mfma_f32_16x16x32_bf16(a, bb, acc[mt], 0, 0, 0);
      }
    }
    if (g < G - 1) stage(g + 1, s[(g + 1) & 1]);
    __syncthreads();
  }

  const int p = p0 + pt * 16 + l15;
  #pragma unroll
  for (int mt = 0; mt < 4; ++mt) {
    #pragma unroll
    for (int r = 0; r < 4; ++r) {
      int oo = o0 + mt * 16 + l4 * 4 + r;
      out[((size_t)b * C + oo) * HW + p] = acc[mt][r] + bias[oo];
    }
  }
}

extern "C" void kernel_launch(void* const* d_in, const int* in_sizes, int n_in,
                              void* d_out, int out_size, void* d_ws, size_t ws_size,
                              hipStream_t stream) {
  const float* x_main  = (const float*)d_in[0];
  const float* inpfeat = (const float*)d_in[1];
  const float* w1a = (const float*)d_in[2];
  const float* b1a = (const float*)d_in[3];
  const float* g1  = (const float*)d_in[4];
  const float* be1 = (const float*)d_in[5];
  const float* w1b = (const float*)d_in[6];
  const float* b1b = (const float*)d_in[7];
  const float* g2  = (const float*)d_in[8];
  const float* be2 = (const float*)d_in[9];
  const float* w1c = (const float*)d_in[10];
  const float* b1c = (const float*)d_in[11];
  const float* w2  = (const float*)d_in[12];
  const float* b2  = (const float*)d_in[13];
  const float* g3  = (const float*)d_in[14];
  const float* be3 = (const float*)d_in[15];
  const float* w_off = (const float*)d_in[16];
  const float* b_off = (const float*)d_in[17];
  const float* w_dcn = (const float*)d_in[18];
  const float* b_dcn = (const float*)d_in[19];

  float* warp_out = (float*)d_out;                      // output 0 [B,C,H,W]
  float* off_out  = warp_out + (size_t)B * C * HW;      // output 1 [B,C,H,W]

  // ---- workspace carve (bytes) ----
  char* ws = (char*)d_ws;
  float* r_inp = (float*)ws;                            //  2 MB [B][CC][HW]; later wTd
  float* fA    = (float*)(ws + (2u << 20));             // 16 MB [B][C][HW] (also co)
  short* T     = (short*)(ws + (2u << 20) + (16u << 20));   // 9.44 MB bf16 (also xmT)
  char*  wbase = ws + (2u << 20) + (16u << 20) + 9437184;
  short* wT1a  = (short*)(wbase);                       // 256*288
  short* wT1c  = (short*)(wbase + 294912);              // 256*256
  short* wT2   = (short*)(wbase + 294912 + 131072);     // 9*256*256
  short* wToff = (short*)(wbase + 294912 + 131072 + 1179648);  // 9*216*256
  float2* stats = (float2*)(wbase + 294912 + 131072 + 1179648 + 995328);  // 128 float2
  short* wTd   = (short*)r_inp;                         // [g][tap][o][32] (after r_inp dead)
  float* fB = warp_out;   // scratch until final deform write
  float* co = fA;

  k_wt<1><<<dim3((256 * 288 + 255) / 256), 256, 0, stream>>>(w1a, wT1a, 256, 288);
  k_wt<1><<<dim3(256), 256, 0, stream>>>(w1c, wT1c, 256, 256);
  k_wt<9><<<dim3(256), 256, 0, stream>>>(w2, wT2, 256, 256);
  k_wt<9><<<dim3(216), 256, 0, stream>>>(w_off, wToff, 216, 256);

  k_resize<<<dim3((B * CC * HW) / 256), 256, 0, stream>>>(inpfeat, r_inp);
  k_transpose<<<dim3(HW / 64, 1, B), 256, 0, stream>>>(r_inp, T, CC, 288, 0);
  k_transpose<<<dim3(HW / 64, 8, B), 256, 0, stream>>>(x_main, T, C, 288, 32);
  k_mfma_conv<288, 256, 1><<<dim3(HW / 128, 4, B), 256, 0, stream>>>(T, wT1a, b1a, fA);
  k_wt_dcn<<<dim3(256), 256, 0, stream>>>(w_dcn, wTd);   // r_inp now dead
  k_gn_silu<<<dim3(GN, B), 256, 0, stream>>>(fA, fA, g1, be1);
  k_dw7<<<dim3(HW / 1024, C, B), 256, 0, stream>>>(fA, w1b, b1b, fB);
  // gn2 fused: stats + (apply + SiLU + bf16 transpose)
  k_gn_stats<<<dim3(GN, B), 256, 0, stream>>>(fB, stats);
  k_gnt<0><<<dim3(HW / 64, B), 256, 0, stream>>>(fB, stats, g2, be2, T, nullptr);
  k_mfma_conv<256, 256, 1><<<dim3(HW / 128, 4, B), 256, 0, stream>>>(T, wT1c, b1c, fA);
  k_transpose<<<dim3(HW / 64, 8, B), 256, 0, stream>>>(fA, T, C, 256, 0);
  k_mfma_conv<256, 256, 9><<<dim3(HW / 128, 4, B), 256, 0, stream>>>(T, wT2, b2, fB);
  // gn3 fused: stats + (apply + SiLU + fp32 off_out + bf16 transpose)
  k_gn_stats<<<dim3(GN, B), 256, 0, stream>>>(fB, stats);
  k_gnt<1><<<dim3(HW / 64, B), 256, 0, stream>>>(fB, stats, g3, be3, T, off_out);
  k_mfma_conv<256, 216, 9><<<dim3(HW / 128, 4, B), 256, 0, stream>>>(T, wToff, b_off, co);
  // T dead -> reuse as xmT [B][HW][256] bf16
  k_transpose<<<dim3(HW / 64, 8, B), 256, 0, stream>>>(x_main, T, C, 256, 0);
  k_deform_mfma<<<dim3(HW / 32, B), 512, 0, stream>>>(T, co, wTd, b_dcn, warp_out);
}